// Round 2
// baseline (1086.753 us; speedup 1.0000x reference)
//
#include <hip/hip_runtime.h>
#include <hip/hip_bf16.h>

typedef unsigned short u16;
typedef unsigned int u32;
typedef unsigned char u8;
typedef __attribute__((ext_vector_type(4))) float f32x4;
typedef __attribute__((ext_vector_type(8))) short s16x8;

#define HG_N   200000
#define HG_E   50000
#define HG_NNZ 2000000
#define HG_F   256
#define HG_D   128

// ---- binned CSR build geometry ----
// Buckets are pow-2 key spans so one merged kernel handles both directions
// with a runtime shift (block-uniform): E-dir bucket = e >> 8 (196 buckets of
// 256 edges), V-dir bucket = v >> 10 (196 buckets of 1024 vertices).
// Expected records/bucket = 10240; CAP gives ~20 sigma headroom.
#define NB     256
#define CHUNK  4096           // pairs per pass1 block (32KB LDS stage -> 3 blocks/CU)
#define CAP    12288
#define NSTRIP (HG_N / 16)    // 12500 GEMM row-strips

__device__ __forceinline__ u32 f2bf_rne(float x) {
  u32 u = __float_as_uint(x);
  return (u + 0x7fffu + ((u >> 16) & 1u)) >> 16;
}
__device__ __forceinline__ float bf2f(u32 bits) { return __uint_as_float(bits << 16); }
__device__ __forceinline__ float bf_lo(u32 u) { return __uint_as_float(u << 16); }
__device__ __forceinline__ float bf_hi(u32 u) { return __uint_as_float(u & 0xffff0000u); }

// ---------------- dtype detection ----------------
__global__ void detect_dtype(const u16* __restrict__ f, int* __restrict__ flag) {
  __shared__ int acc[4];
  int t = threadIdx.x;
  int bad = 0;
  for (int i = t; i < 2048; i += 256) {
    u32 u = f[2 * i];
    int e = (u >> 7) & 0xff;
    if (e < 0x70 || e > 0x88) bad++;
  }
#pragma unroll
  for (int off = 32; off; off >>= 1) bad += __shfl_down(bad, off);
  if ((t & 63) == 0) acc[t >> 6] = bad;
  __syncthreads();
  if (t == 0) flag[0] = (acc[0] + acc[1] + acc[2] + acc[3] > 200) ? 1 : 0;
}

// ---------------- CSR build: bucket-binned two-pass scatter ----------------
// Pass 1 (both directions in one launch, 2*489 blocks): partition pairs into
// NB buckets by destination-segment id with LDS staging so the binned array
// is written in coalesced runs. Record: x = col | (local_seg_id << 18)
// (col < 2^18, local < 2^10), y = fp32 weight bits (bit-exact).

__global__ __launch_bounds__(256) void bin_pass1(
    const int* __restrict__ pv, const int* __restrict__ pe,
    const void* __restrict__ wve, const void* __restrict__ wev,
    const int* __restrict__ flag,
    int2* __restrict__ binned0, int2* __restrict__ binned1,
    int* __restrict__ gcur, int nb1) {
  __shared__ int cnt[NB], lbase[NB], run[NB], gbase[NB], sc[NB];
  __shared__ int2 stage[CHUNK];     // 32 KB, records sorted by bucket
  __shared__ u8 sb[CHUNK];          // bucket id per staged record
  int t = threadIdx.x;
  int dir = blockIdx.x >= nb1;
  int cb = dir ? blockIdx.x - nb1 : blockIdx.x;
  int base = cb * CHUNK;
  int n = HG_NNZ - base; if (n > CHUNK) n = CHUNK;
  int shift = dir ? 10 : 8;
  int mask = (1 << shift) - 1;
  const int* key = dir ? pv : pe;   // segment id (destination)
  const int* col = dir ? pe : pv;   // gather column
  const float* wf = (const float*)(dir ? wev : wve);
  const u16* wh = (const u16*)(dir ? wev : wve);
  int2* binned = dir ? binned1 : binned0;
  int* gc = gcur + (dir ? NB : 0);
  int fp32 = *flag;

  cnt[t] = 0;
  __syncthreads();

  // sweep 1: LDS histogram of buckets
#pragma unroll 4
  for (int k = 0; k < CHUNK / 256; ++k) {
    int p = base + k * 256 + t;
    if (p < HG_NNZ) atomicAdd(&cnt[key[p] >> shift], 1);
  }
  __syncthreads();

  // exclusive block scan of cnt -> lbase
  sc[t] = cnt[t];
  __syncthreads();
  for (int off = 1; off < NB; off <<= 1) {
    int x = (t >= off) ? sc[t - off] : 0;
    __syncthreads();
    sc[t] += x;
    __syncthreads();
  }
  lbase[t] = sc[t] - cnt[t];
  run[t] = lbase[t];
  gbase[t] = atomicAdd(&gc[t], cnt[t]);  // reserve run range per bucket
  __syncthreads();

  // sweep 2: rank + stage records into LDS (bucket-sorted)
#pragma unroll 4
  for (int k = 0; k < CHUNK / 256; ++k) {
    int p = base + k * 256 + t;
    if (p < HG_NNZ) {
      int kk = key[p];
      int b = kk >> shift;
      int local = kk & mask;
      float w = fp32 ? wf[p] : bf2f(wh[p]);
      int s = atomicAdd(&run[b], 1);
      int2 r; r.x = col[p] | (local << 18); r.y = __float_as_int(w);
      stage[s] = r;
      sb[s] = (u8)b;
    }
  }
  __syncthreads();

  // coalesced write-out of bucket-sorted runs
  for (int i = t; i < n; i += 256) {
    int bb = sb[i];
    int d = gbase[bb] + (i - lbase[bb]);
    if (d < CAP) binned[(size_t)bb * CAP + d] = stage[i];
  }
}

// Pass 2 (both directions, 512 blocks): one block per bucket. Block
// exclusively owns its segment range and its ~96KB slice of the final entry
// array -> scattered writes stay XCD-local and write back ~1x. Also derives
// rp[] for its range.
__global__ __launch_bounds__(256) void csr_pass2(
    const int2* __restrict__ binned0, const int2* __restrict__ binned1,
    const int* __restrict__ gcur,
    int* __restrict__ rpe, int* __restrict__ rpv,
    int2* __restrict__ ente, int2* __restrict__ entv) {
  __shared__ int cc[NB], sc[NB];
  __shared__ int lcnt[1024], lrp[1024];
  int t = threadIdx.x;
  int dir = blockIdx.x >> 8;
  int b = blockIdx.x & 255;
  int shift = dir ? 10 : 8;
  int span = 1 << shift;
  int K = dir ? HG_N : HG_E;
  const int2* binned = dir ? binned1 : binned0;
  const int* gc = gcur + (dir ? NB : 0);
  int* rp = dir ? rpv : rpe;
  int2* ent = dir ? entv : ente;

  // scan bucket totals to get this bucket's global CSR base
  cc[t] = gc[t];
  __syncthreads();
  sc[t] = cc[t];
  __syncthreads();
  for (int off = 1; off < NB; off <<= 1) {
    int x = (t >= off) ? sc[t - off] : 0;
    __syncthreads();
    sc[t] += x;
    __syncthreads();
  }
  int gb = sc[b] - cc[b];
  int total = cc[b]; if (total > CAP) total = CAP;

  for (int j = t; j < 1024; j += 256) lcnt[j] = 0;
  __syncthreads();

  int kb = b << shift;
  int span_act = K - kb; if (span_act > span) span_act = span;
  const int2* rec = binned + (size_t)b * CAP;

  // local histogram over this bucket's segments
#pragma unroll 4
  for (int i = t; i < total; i += 256) atomicAdd(&lcnt[rec[i].x >> 18], 1);
  __syncthreads();

  // exclusive scan of lcnt[0..1024) -> lrp
  int vals[4], s0 = 0;
#pragma unroll
  for (int j = 0; j < 4; ++j) { vals[j] = lcnt[t * 4 + j]; s0 += vals[j]; }
  sc[t] = s0;
  __syncthreads();
  for (int off = 1; off < NB; off <<= 1) {
    int x = (t >= off) ? sc[t - off] : 0;
    __syncthreads();
    sc[t] += x;
    __syncthreads();
  }
  int running = sc[t] - s0;
#pragma unroll
  for (int j = 0; j < 4; ++j) { lrp[t * 4 + j] = running; running += vals[j]; }
  __syncthreads();

  // emit row pointers (boundary rows written consistently by both neighbors)
  for (int j = t; j <= span_act; j += 256)
    rp[kb + j] = gb + ((j < 1024) ? lrp[j] : total);
  __syncthreads();

  // scatter into this bucket's CSR slice
#pragma unroll 4
  for (int i = t; i < total; i += 256) {
    int2 r = rec[i];
    int local = r.x >> 18;
    int slot = gb + atomicAdd(&lrp[local], 1);
    int2 o; o.x = r.x & 0x3FFFF; o.y = r.y;
    ent[slot] = o;
  }
}

// ---------------- GEMM: x = feats @ W + b (bf16 MFMA, bf16 out) ----------------

__global__ void transpose_w_kernel(const void* __restrict__ W, u16* __restrict__ WT,
                                   const int* __restrict__ flag) {
  int idx = blockIdx.x * 256 + threadIdx.x;  // 256*128 = 32768 elems
  u16 v = (*flag) ? (u16)f2bf_rne(((const float*)W)[idx]) : ((const u16*)W)[idx];
  WT[(idx & 127) * 256 + (idx >> 7)] = v;
}

// 512-thread blocks, 64KB LDS -> 2 blocks/CU = 16 waves/CU (was 8; VGPR<=128
// enforced by launch_bounds). A-fragments rotate in place: after the 8 MFMAs
// that consume a[k0], the NEXT strip's load is issued into the same register,
// so loads always precede the C-stores in program order and the pre-MFMA
// waitcnt never has to drain the store queue (the old structure serialized on
// exactly that: ~1.2 TB/s with 90% idle pipes).
template <bool FP32>
__global__ __launch_bounds__(512, 4) void gemm_kernel(
    const void* __restrict__ A,    // feats [N][256] (bf16 or fp32 per flag)
    const u16* __restrict__ WT,    // bf16 [128][256] (W transposed, canonical)
    const void* __restrict__ bias, // [128]
    const int* __restrict__ flag,
    u16* __restrict__ xb) {        // bf16 [N][128]
  if ((*flag != 0) != FP32) return;
  __shared__ u16 wt[32768];
  {
    const uint4* src = (const uint4*)WT;  // 4096 granules, 32 per row
    uint4* d = (uint4*)wt;
    for (int i = threadIdx.x; i < 4096; i += 512) {
      int r = i >> 5, g = i & 31;
      d[(r << 5) | (g ^ (r & 31))] = src[i];
    }
  }
  __syncthreads();
  int lane = threadIdx.x & 63;
  int q = lane >> 4, m = lane & 15;
  int wave0 = blockIdx.x * 8 + (threadIdx.x >> 6);
  int nwaves = gridDim.x * 8;
  const s16x8* wlds = (const s16x8*)wt;

  float bv[8];
#pragma unroll
  for (int n = 0; n < 8; ++n)
    bv[n] = FP32 ? ((const float*)bias)[n * 16 + m] : bf2f(((const u16*)bias)[n * 16 + m]);

  auto aload = [&](int s, int k0) -> s16x8 {
    if (FP32) {
      const float* ar = (const float*)A + (size_t)(s * 16 + m) * 256 + q * 8 + k0 * 32;
      float4 p0 = *(const float4*)ar;
      float4 p1 = *(const float4*)(ar + 4);
      s16x8 r;
      r[0] = (short)f2bf_rne(p0.x); r[1] = (short)f2bf_rne(p0.y);
      r[2] = (short)f2bf_rne(p0.z); r[3] = (short)f2bf_rne(p0.w);
      r[4] = (short)f2bf_rne(p1.x); r[5] = (short)f2bf_rne(p1.y);
      r[6] = (short)f2bf_rne(p1.z); r[7] = (short)f2bf_rne(p1.w);
      return r;
    } else {
      return *(const s16x8*)((const u16*)A + (size_t)(s * 16 + m) * 256 + q * 8 + k0 * 32);
    }
  };

  s16x8 a[8];
  int strip = wave0;
  if (strip >= NSTRIP) return;
#pragma unroll
  for (int k0 = 0; k0 < 8; ++k0) a[k0] = aload(strip, k0);

  for (; strip < NSTRIP; strip += nwaves) {
    int snext = strip + nwaves;
    int sclamp = (snext < NSTRIP) ? snext : strip;  // tail: harmless re-read
    f32x4 acc[8];
#pragma unroll
    for (int n = 0; n < 8; ++n) acc[n] = (f32x4){0.f, 0.f, 0.f, 0.f};
#pragma unroll
    for (int k0 = 0; k0 < 8; ++k0) {
      int g = (k0 << 2) | q;
#pragma unroll
      for (int n = 0; n < 8; ++n) {
        int rr = n * 16 + m;  // B col index; WT row
        s16x8 b = wlds[(rr << 5) | (g ^ (rr & 31))];
        acc[n] = __builtin_amdgcn_mfma_f32_16x16x32_bf16(a[k0], b, acc[n], 0, 0, 0);
      }
      a[k0] = aload(sclamp, k0);  // rotate next strip's frag into dead reg
    }
#pragma unroll
    for (int n = 0; n < 8; ++n) {
#pragma unroll
      for (int r = 0; r < 4; ++r) {
        // C/D layout: col = lane&15, row = (lane>>4)*4 + r  [m89/m91 verified]
        xb[(size_t)(strip * 16 + q * 4 + r) * 128 + n * 16 + m] = (u16)f2bf_rne(acc[n][r] + bv[n]);
      }
    }
  }
}

// ---------------- Pull aggregation over bf16 rows, fp32 accumulate ----------------

__global__ __launch_bounds__(256) void pull_kernel(
    const int* __restrict__ rp, const int2* __restrict__ ent,
    const u32* __restrict__ src, u32* __restrict__ dst, int nrows) {
  int row = blockIdx.x * 4 + (threadIdx.x >> 6);
  if (row >= nrows) return;
  int lane = threadIdx.x & 63;
  int beg = rp[row], end = rp[row + 1];
  float ax = 0.f, ay = 0.f, den = 0.f;
  int j = beg;
  for (; j + 4 <= end; j += 4) {
    int2 e0 = ent[j], e1 = ent[j + 1], e2 = ent[j + 2], e3 = ent[j + 3];
    u32 u0 = src[(size_t)e0.x * 64 + lane];
    u32 u1 = src[(size_t)e1.x * 64 + lane];
    u32 u2 = src[(size_t)e2.x * 64 + lane];
    u32 u3 = src[(size_t)e3.x * 64 + lane];
    float w0 = __int_as_float(e0.y), w1 = __int_as_float(e1.y);
    float w2 = __int_as_float(e2.y), w3 = __int_as_float(e3.y);
    den += (w0 + w1) + (w2 + w3);
    ax = fmaf(w0, bf_lo(u0), ax); ay = fmaf(w0, bf_hi(u0), ay);
    ax = fmaf(w1, bf_lo(u1), ax); ay = fmaf(w1, bf_hi(u1), ay);
    ax = fmaf(w2, bf_lo(u2), ax); ay = fmaf(w2, bf_hi(u2), ay);
    ax = fmaf(w3, bf_lo(u3), ax); ay = fmaf(w3, bf_hi(u3), ay);
  }
  for (; j < end; ++j) {
    int2 e0 = ent[j];
    u32 u0 = src[(size_t)e0.x * 64 + lane];
    float w0 = __int_as_float(e0.y);
    den += w0;
    ax = fmaf(w0, bf_lo(u0), ax);
    ay = fmaf(w0, bf_hi(u0), ay);
  }
  float inv = 1.0f / fmaxf(den, 1e-12f);
  dst[(size_t)row * 64 + lane] = f2bf_rne(ax * inv) | (f2bf_rne(ay * inv) << 16);
}

// ---------------- Fused final pull + softmax ----------------
// The last e2v hop feeds straight into the row softmax: each 64-lane wave
// already holds the full 128-wide row (2 vals/lane), so fuse and skip the
// 51.2MB xb write + 51.2MB re-read and one dispatch. Softmax sees fp32
// pre-rounded values (slightly more accurate than the bf16 round-trip).
__global__ __launch_bounds__(256) void pull_softmax_kernel(
    const int* __restrict__ rp, const int2* __restrict__ ent,
    const u32* __restrict__ src, void* __restrict__ out,
    const int* __restrict__ flag, int nrows) {
  int row = blockIdx.x * 4 + (threadIdx.x >> 6);
  if (row >= nrows) return;
  int lane = threadIdx.x & 63;
  int beg = rp[row], end = rp[row + 1];
  float ax = 0.f, ay = 0.f, den = 0.f;
  int j = beg;
  for (; j + 4 <= end; j += 4) {
    int2 e0 = ent[j], e1 = ent[j + 1], e2 = ent[j + 2], e3 = ent[j + 3];
    u32 u0 = src[(size_t)e0.x * 64 + lane];
    u32 u1 = src[(size_t)e1.x * 64 + lane];
    u32 u2 = src[(size_t)e2.x * 64 + lane];
    u32 u3 = src[(size_t)e3.x * 64 + lane];
    float w0 = __int_as_float(e0.y), w1 = __int_as_float(e1.y);
    float w2 = __int_as_float(e2.y), w3 = __int_as_float(e3.y);
    den += (w0 + w1) + (w2 + w3);
    ax = fmaf(w0, bf_lo(u0), ax); ay = fmaf(w0, bf_hi(u0), ay);
    ax = fmaf(w1, bf_lo(u1), ax); ay = fmaf(w1, bf_hi(u1), ay);
    ax = fmaf(w2, bf_lo(u2), ax); ay = fmaf(w2, bf_hi(u2), ay);
    ax = fmaf(w3, bf_lo(u3), ax); ay = fmaf(w3, bf_hi(u3), ay);
  }
  for (; j < end; ++j) {
    int2 e0 = ent[j];
    u32 u0 = src[(size_t)e0.x * 64 + lane];
    float w0 = __int_as_float(e0.y);
    den += w0;
    ax = fmaf(w0, bf_lo(u0), ax);
    ay = fmaf(w0, bf_hi(u0), ay);
  }
  float inv = 1.0f / fmaxf(den, 1e-12f);
  float v0 = ax * inv, v1 = ay * inv;
  float mx = fmaxf(v0, v1);
#pragma unroll
  for (int off = 32; off; off >>= 1) mx = fmaxf(mx, __shfl_xor(mx, off));
  float e0 = __expf(v0 - mx), e1 = __expf(v1 - mx);
  float s = e0 + e1;
#pragma unroll
  for (int off = 32; off; off >>= 1) s += __shfl_xor(s, off);
  float is = 1.0f / s;
  if (*flag) {
    float2 o; o.x = e0 * is; o.y = e1 * is;
    ((float2*)out)[(size_t)row * 64 + lane] = o;
  } else {
    ((u32*)out)[(size_t)row * 64 + lane] = f2bf_rne(e0 * is) | (f2bf_rne(e1 * is) << 16);
  }
}

// ---------------- launch ----------------

extern "C" void kernel_launch(void* const* d_in, const int* in_sizes, int n_in,
                              void* d_out, int out_size, void* d_ws, size_t ws_size,
                              hipStream_t stream) {
  const void* feats = d_in[0];
  const void* W = d_in[1];
  const void* bias = d_in[2];
  const void* wve = d_in[3];
  const void* wev = d_in[4];
  const int* pv = (const int*)d_in[5];
  const int* pe = (const int*)d_in[6];

  char* p = (char*)d_ws;
  auto alloc = [&](size_t b) { char* r = p; p += (b + 255) & ~(size_t)255; return r; };
  int* flag = (int*)alloc(4);
  // big region: binned scratch (2 x 24MB, used only during CSR build) aliases
  // xb (51.2MB) + yb (12.8MB), first written by the GEMM afterwards.
  char* big = alloc(64000000);
  u16* xb = (u16*)big;                          // bf16 [N][128]
  u16* yb = (u16*)(big + 51200000);             // bf16 [E][128]
  int2* binned0 = (int2*)big;                   // NB*CAP edge-dir records
  int2* binned1 = binned0 + (size_t)NB * CAP;   // NB*CAP vertex-dir records
  u16* wtg = (u16*)alloc(HG_D * HG_F * 2);      // canonical W^T bf16
  int* rpe = (int*)alloc((HG_E + 1) * 4);
  int* rpv = (int*)alloc((HG_N + 1) * 4);
  int2* ente = (int2*)alloc((size_t)HG_NNZ * 8);
  int2* entv = (int2*)alloc((size_t)HG_NNZ * 8);
  int* gcur = (int*)alloc(2 * NB * 4);
  // total ~97 MB

  detect_dtype<<<1, 256, 0, stream>>>((const u16*)feats, flag);

  // CSR build: bin -> per-bucket scatter (both directions merged per launch)
  hipMemsetAsync(gcur, 0, 2 * NB * 4, stream);
  int nb1 = (HG_NNZ + CHUNK - 1) / CHUNK;
  bin_pass1<<<2 * nb1, 256, 0, stream>>>(pv, pe, wve, wev, flag, binned0, binned1, gcur, nb1);
  csr_pass2<<<2 * NB, 256, 0, stream>>>(binned0, binned1, gcur, rpe, rpv, ente, entv);

  // x = feats @ W + b
  transpose_w_kernel<<<128, 256, 0, stream>>>(W, wtg, flag);
  gemm_kernel<false><<<512, 512, 0, stream>>>(feats, wtg, bias, flag, xb);
  gemm_kernel<true><<<512, 512, 0, stream>>>(feats, wtg, bias, flag, xb);

  // two hops of weighted-mean aggregation (last hop fused with softmax)
  pull_kernel<<<HG_E / 4, 256, 0, stream>>>(rpe, ente, (const u32*)xb, (u32*)yb, HG_E);
  pull_kernel<<<HG_N / 4, 256, 0, stream>>>(rpv, entv, (const u32*)yb, (u32*)xb, HG_N);
  pull_kernel<<<HG_E / 4, 256, 0, stream>>>(rpe, ente, (const u32*)xb, (u32*)yb, HG_E);
  pull_softmax_kernel<<<HG_N / 4, 256, 0, stream>>>(rpv, entv, (const u32*)yb, d_out, flag, HG_N);
}

// Round 3
// 846.793 us; speedup vs baseline: 1.2834x; 1.2834x over previous
//
#include <hip/hip_runtime.h>
#include <hip/hip_bf16.h>

typedef unsigned short u16;
typedef unsigned int u32;
typedef unsigned char u8;
typedef __attribute__((ext_vector_type(4))) float f32x4;
typedef __attribute__((ext_vector_type(8))) short s16x8;

#define HG_N   200000
#define HG_E   50000
#define HG_NNZ 2000000
#define HG_F   256
#define HG_D   128

// ---- binned CSR build geometry ----
#define NB     256
#define CHUNK  4096           // pairs per pass1 block (32KB LDS stage -> 3 blocks/CU)
#define CAP    12288
#define NSTRIP (HG_N / 16)    // 12500 GEMM row-strips

__device__ __forceinline__ u32 f2bf_rne(float x) {
  u32 u = __float_as_uint(x);
  return (u + 0x7fffu + ((u >> 16) & 1u)) >> 16;
}
__device__ __forceinline__ float bf2f(u32 bits) { return __uint_as_float(bits << 16); }
__device__ __forceinline__ float bf_lo(u32 u) { return __uint_as_float(u << 16); }
__device__ __forceinline__ float bf_hi(u32 u) { return __uint_as_float(u & 0xffff0000u); }

// ---------------- dtype detection ----------------
__global__ void detect_dtype(const u16* __restrict__ f, int* __restrict__ flag) {
  __shared__ int acc[4];
  int t = threadIdx.x;
  int bad = 0;
  for (int i = t; i < 2048; i += 256) {
    u32 u = f[2 * i];
    int e = (u >> 7) & 0xff;
    if (e < 0x70 || e > 0x88) bad++;
  }
#pragma unroll
  for (int off = 32; off; off >>= 1) bad += __shfl_down(bad, off);
  if ((t & 63) == 0) acc[t >> 6] = bad;
  __syncthreads();
  if (t == 0) flag[0] = (acc[0] + acc[1] + acc[2] + acc[3] > 200) ? 1 : 0;
}

// ---------------- CSR build: bucket-binned two-pass scatter ----------------

__global__ __launch_bounds__(256) void bin_pass1(
    const int* __restrict__ pv, const int* __restrict__ pe,
    const void* __restrict__ wve, const void* __restrict__ wev,
    const int* __restrict__ flag,
    int2* __restrict__ binned0, int2* __restrict__ binned1,
    int* __restrict__ gcur, int nb1) {
  __shared__ int cnt[NB], lbase[NB], run[NB], gbase[NB], sc[NB];
  __shared__ int2 stage[CHUNK];     // 32 KB, records sorted by bucket
  __shared__ u8 sb[CHUNK];          // bucket id per staged record
  int t = threadIdx.x;
  int dir = blockIdx.x >= nb1;
  int cb = dir ? blockIdx.x - nb1 : blockIdx.x;
  int base = cb * CHUNK;
  int n = HG_NNZ - base; if (n > CHUNK) n = CHUNK;
  int shift = dir ? 10 : 8;
  int mask = (1 << shift) - 1;
  const int* key = dir ? pv : pe;   // segment id (destination)
  const int* col = dir ? pe : pv;   // gather column
  const float* wf = (const float*)(dir ? wev : wve);
  const u16* wh = (const u16*)(dir ? wev : wve);
  int2* binned = dir ? binned1 : binned0;
  int* gc = gcur + (dir ? NB : 0);
  int fp32 = *flag;

  cnt[t] = 0;
  __syncthreads();

  // sweep 1: LDS histogram of buckets
#pragma unroll 4
  for (int k = 0; k < CHUNK / 256; ++k) {
    int p = base + k * 256 + t;
    if (p < HG_NNZ) atomicAdd(&cnt[key[p] >> shift], 1);
  }
  __syncthreads();

  // exclusive block scan of cnt -> lbase
  sc[t] = cnt[t];
  __syncthreads();
  for (int off = 1; off < NB; off <<= 1) {
    int x = (t >= off) ? sc[t - off] : 0;
    __syncthreads();
    sc[t] += x;
    __syncthreads();
  }
  lbase[t] = sc[t] - cnt[t];
  run[t] = lbase[t];
  gbase[t] = atomicAdd(&gc[t], cnt[t]);  // reserve run range per bucket
  __syncthreads();

  // sweep 2: rank + stage records into LDS (bucket-sorted)
#pragma unroll 4
  for (int k = 0; k < CHUNK / 256; ++k) {
    int p = base + k * 256 + t;
    if (p < HG_NNZ) {
      int kk = key[p];
      int b = kk >> shift;
      int local = kk & mask;
      float w = fp32 ? wf[p] : bf2f(wh[p]);
      int s = atomicAdd(&run[b], 1);
      int2 r; r.x = col[p] | (local << 18); r.y = __float_as_int(w);
      stage[s] = r;
      sb[s] = (u8)b;
    }
  }
  __syncthreads();

  // coalesced write-out of bucket-sorted runs
  for (int i = t; i < n; i += 256) {
    int bb = sb[i];
    int d = gbase[bb] + (i - lbase[bb]);
    if (d < CAP) binned[(size_t)bb * CAP + d] = stage[i];
  }
}

// Pass 2 (both directions, 512 blocks): one block per bucket.
__global__ __launch_bounds__(256) void csr_pass2(
    const int2* __restrict__ binned0, const int2* __restrict__ binned1,
    const int* __restrict__ gcur,
    int* __restrict__ rpe, int* __restrict__ rpv,
    int2* __restrict__ ente, int2* __restrict__ entv) {
  __shared__ int cc[NB], sc[NB];
  __shared__ int lcnt[1024], lrp[1024];
  int t = threadIdx.x;
  int dir = blockIdx.x >> 8;
  int b = blockIdx.x & 255;
  int shift = dir ? 10 : 8;
  int span = 1 << shift;
  int K = dir ? HG_N : HG_E;
  const int2* binned = dir ? binned1 : binned0;
  const int* gc = gcur + (dir ? NB : 0);
  int* rp = dir ? rpv : rpe;
  int2* ent = dir ? entv : ente;

  // scan bucket totals to get this bucket's global CSR base
  cc[t] = gc[t];
  __syncthreads();
  sc[t] = cc[t];
  __syncthreads();
  for (int off = 1; off < NB; off <<= 1) {
    int x = (t >= off) ? sc[t - off] : 0;
    __syncthreads();
    sc[t] += x;
    __syncthreads();
  }
  int gb = sc[b] - cc[b];
  int total = cc[b]; if (total > CAP) total = CAP;

  for (int j = t; j < 1024; j += 256) lcnt[j] = 0;
  __syncthreads();

  int kb = b << shift;
  int span_act = K - kb; if (span_act > span) span_act = span;
  const int2* rec = binned + (size_t)b * CAP;

  // local histogram over this bucket's segments
#pragma unroll 4
  for (int i = t; i < total; i += 256) atomicAdd(&lcnt[rec[i].x >> 18], 1);
  __syncthreads();

  // exclusive scan of lcnt[0..1024) -> lrp
  int vals[4], s0 = 0;
#pragma unroll
  for (int j = 0; j < 4; ++j) { vals[j] = lcnt[t * 4 + j]; s0 += vals[j]; }
  sc[t] = s0;
  __syncthreads();
  for (int off = 1; off < NB; off <<= 1) {
    int x = (t >= off) ? sc[t - off] : 0;
    __syncthreads();
    sc[t] += x;
    __syncthreads();
  }
  int running = sc[t] - s0;
#pragma unroll
  for (int j = 0; j < 4; ++j) { lrp[t * 4 + j] = running; running += vals[j]; }
  __syncthreads();

  // emit row pointers (boundary rows written consistently by both neighbors)
  for (int j = t; j <= span_act; j += 256)
    rp[kb + j] = gb + ((j < 1024) ? lrp[j] : total);
  __syncthreads();

  // scatter into this bucket's CSR slice
#pragma unroll 4
  for (int i = t; i < total; i += 256) {
    int2 r = rec[i];
    int local = r.x >> 18;
    int slot = gb + atomicAdd(&lrp[local], 1);
    int2 o; o.x = r.x & 0x3FFFF; o.y = r.y;
    ent[slot] = o;
  }
}

// ---------------- GEMM: x = feats @ W + b (bf16 MFMA, bf16 out) ----------------

__global__ void transpose_w_kernel(const void* __restrict__ W, u16* __restrict__ WT,
                                   const int* __restrict__ flag) {
  int idx = blockIdx.x * 256 + threadIdx.x;  // 256*128 = 32768 elems
  u16 v = (*flag) ? (u16)f2bf_rne(((const float*)W)[idx]) : ((const u16*)W)[idx];
  WT[(idx & 127) * 256 + (idx >> 7)] = v;
}

// 256-thread blocks, NO min-occupancy bound (round 2's __launch_bounds__(512,4)
// clamped VGPR to 64 -> the a[]/acc working set spilled to scratch: FETCH
// 100->539MB, WRITE 50->316MB, 342us). LDS (64KB) caps residency at 2
// blocks/CU = 8 waves/CU no matter what, so VGPR is free up to 256 at that
// occupancy — use it for an explicit ping-pong prefetch: issue ALL 8 of the
// next strip's 16B A-loads before this strip's 64 MFMAs. Loads sit in flight
// across compute+store, so only iteration 0's latency is exposed.
template <bool FP32>
__global__ __launch_bounds__(256) void gemm_kernel(
    const void* __restrict__ A,    // feats [N][256] (bf16 or fp32 per flag)
    const u16* __restrict__ WT,    // bf16 [128][256] (W transposed, canonical)
    const void* __restrict__ bias, // [128]
    const int* __restrict__ flag,
    u16* __restrict__ xb) {        // bf16 [N][128]
  if ((*flag != 0) != FP32) return;
  __shared__ u16 wt[32768];
  {
    const uint4* src = (const uint4*)WT;  // 4096 granules, 32 per row
    uint4* d = (uint4*)wt;
    for (int i = threadIdx.x; i < 4096; i += 256) {
      int r = i >> 5, g = i & 31;
      d[(r << 5) | (g ^ (r & 31))] = src[i];
    }
  }
  __syncthreads();
  int lane = threadIdx.x & 63;
  int q = lane >> 4, m = lane & 15;
  int wave0 = blockIdx.x * 4 + (threadIdx.x >> 6);
  int nwaves = gridDim.x * 4;
  const s16x8* wlds = (const s16x8*)wt;

  float bv[8];
#pragma unroll
  for (int n = 0; n < 8; ++n)
    bv[n] = FP32 ? ((const float*)bias)[n * 16 + m] : bf2f(((const u16*)bias)[n * 16 + m]);

  auto aload = [&](int s, int k0) -> s16x8 {
    if (FP32) {
      const float* ar = (const float*)A + (size_t)(s * 16 + m) * 256 + q * 8 + k0 * 32;
      float4 p0 = *(const float4*)ar;
      float4 p1 = *(const float4*)(ar + 4);
      s16x8 r;
      r[0] = (short)f2bf_rne(p0.x); r[1] = (short)f2bf_rne(p0.y);
      r[2] = (short)f2bf_rne(p0.z); r[3] = (short)f2bf_rne(p0.w);
      r[4] = (short)f2bf_rne(p1.x); r[5] = (short)f2bf_rne(p1.y);
      r[6] = (short)f2bf_rne(p1.z); r[7] = (short)f2bf_rne(p1.w);
      return r;
    } else {
      return *(const s16x8*)((const u16*)A + (size_t)(s * 16 + m) * 256 + q * 8 + k0 * 32);
    }
  };

  int strip = wave0;
  if (strip >= NSTRIP) return;
  s16x8 a[8], an[8];
#pragma unroll
  for (int k0 = 0; k0 < 8; ++k0) a[k0] = aload(strip, k0);

  for (; strip < NSTRIP; strip += nwaves) {
    int snext = strip + nwaves;
    int sp = (snext < NSTRIP) ? snext : strip;  // tail: harmless re-read
    // prefetch next strip's fragments (independent of a[] / acc)
#pragma unroll
    for (int k0 = 0; k0 < 8; ++k0) an[k0] = aload(sp, k0);

    f32x4 acc[8];
#pragma unroll
    for (int n = 0; n < 8; ++n) acc[n] = (f32x4){0.f, 0.f, 0.f, 0.f};
#pragma unroll
    for (int k0 = 0; k0 < 8; ++k0) {
      int g = (k0 << 2) | q;
#pragma unroll
      for (int n = 0; n < 8; ++n) {
        int rr = n * 16 + m;  // B col index; WT row
        s16x8 b = wlds[(rr << 5) | (g ^ (rr & 31))];
        acc[n] = __builtin_amdgcn_mfma_f32_16x16x32_bf16(a[k0], b, acc[n], 0, 0, 0);
      }
    }
#pragma unroll
    for (int n = 0; n < 8; ++n) {
#pragma unroll
      for (int r = 0; r < 4; ++r) {
        // C/D layout: col = lane&15, row = (lane>>4)*4 + r  [m89/m91 verified]
        xb[(size_t)(strip * 16 + q * 4 + r) * 128 + n * 16 + m] = (u16)f2bf_rne(acc[n][r] + bv[n]);
      }
    }
#pragma unroll
    for (int k0 = 0; k0 < 8; ++k0) a[k0] = an[k0];
  }
}

// ---------------- Pull aggregation over bf16 rows, fp32 accumulate ----------------

__global__ __launch_bounds__(256) void pull_kernel(
    const int* __restrict__ rp, const int2* __restrict__ ent,
    const u32* __restrict__ src, u32* __restrict__ dst, int nrows) {
  int row = blockIdx.x * 4 + (threadIdx.x >> 6);
  if (row >= nrows) return;
  int lane = threadIdx.x & 63;
  int beg = rp[row], end = rp[row + 1];
  float ax = 0.f, ay = 0.f, den = 0.f;
  int j = beg;
  for (; j + 4 <= end; j += 4) {
    int2 e0 = ent[j], e1 = ent[j + 1], e2 = ent[j + 2], e3 = ent[j + 3];
    u32 u0 = src[(size_t)e0.x * 64 + lane];
    u32 u1 = src[(size_t)e1.x * 64 + lane];
    u32 u2 = src[(size_t)e2.x * 64 + lane];
    u32 u3 = src[(size_t)e3.x * 64 + lane];
    float w0 = __int_as_float(e0.y), w1 = __int_as_float(e1.y);
    float w2 = __int_as_float(e2.y), w3 = __int_as_float(e3.y);
    den += (w0 + w1) + (w2 + w3);
    ax = fmaf(w0, bf_lo(u0), ax); ay = fmaf(w0, bf_hi(u0), ay);
    ax = fmaf(w1, bf_lo(u1), ax); ay = fmaf(w1, bf_hi(u1), ay);
    ax = fmaf(w2, bf_lo(u2), ax); ay = fmaf(w2, bf_hi(u2), ay);
    ax = fmaf(w3, bf_lo(u3), ax); ay = fmaf(w3, bf_hi(u3), ay);
  }
  for (; j < end; ++j) {
    int2 e0 = ent[j];
    u32 u0 = src[(size_t)e0.x * 64 + lane];
    float w0 = __int_as_float(e0.y);
    den += w0;
    ax = fmaf(w0, bf_lo(u0), ax);
    ay = fmaf(w0, bf_hi(u0), ay);
  }
  float inv = 1.0f / fmaxf(den, 1e-12f);
  dst[(size_t)row * 64 + lane] = f2bf_rne(ax * inv) | (f2bf_rne(ay * inv) << 16);
}

// ---------------- Fused final pull + softmax ----------------
__global__ __launch_bounds__(256) void pull_softmax_kernel(
    const int* __restrict__ rp, const int2* __restrict__ ent,
    const u32* __restrict__ src, void* __restrict__ out,
    const int* __restrict__ flag, int nrows) {
  int row = blockIdx.x * 4 + (threadIdx.x >> 6);
  if (row >= nrows) return;
  int lane = threadIdx.x & 63;
  int beg = rp[row], end = rp[row + 1];
  float ax = 0.f, ay = 0.f, den = 0.f;
  int j = beg;
  for (; j + 4 <= end; j += 4) {
    int2 e0 = ent[j], e1 = ent[j + 1], e2 = ent[j + 2], e3 = ent[j + 3];
    u32 u0 = src[(size_t)e0.x * 64 + lane];
    u32 u1 = src[(size_t)e1.x * 64 + lane];
    u32 u2 = src[(size_t)e2.x * 64 + lane];
    u32 u3 = src[(size_t)e3.x * 64 + lane];
    float w0 = __int_as_float(e0.y), w1 = __int_as_float(e1.y);
    float w2 = __int_as_float(e2.y), w3 = __int_as_float(e3.y);
    den += (w0 + w1) + (w2 + w3);
    ax = fmaf(w0, bf_lo(u0), ax); ay = fmaf(w0, bf_hi(u0), ay);
    ax = fmaf(w1, bf_lo(u1), ax); ay = fmaf(w1, bf_hi(u1), ay);
    ax = fmaf(w2, bf_lo(u2), ax); ay = fmaf(w2, bf_hi(u2), ay);
    ax = fmaf(w3, bf_lo(u3), ax); ay = fmaf(w3, bf_hi(u3), ay);
  }
  for (; j < end; ++j) {
    int2 e0 = ent[j];
    u32 u0 = src[(size_t)e0.x * 64 + lane];
    float w0 = __int_as_float(e0.y);
    den += w0;
    ax = fmaf(w0, bf_lo(u0), ax);
    ay = fmaf(w0, bf_hi(u0), ay);
  }
  float inv = 1.0f / fmaxf(den, 1e-12f);
  float v0 = ax * inv, v1 = ay * inv;
  float mx = fmaxf(v0, v1);
#pragma unroll
  for (int off = 32; off; off >>= 1) mx = fmaxf(mx, __shfl_xor(mx, off));
  float e0 = __expf(v0 - mx), e1 = __expf(v1 - mx);
  float s = e0 + e1;
#pragma unroll
  for (int off = 32; off; off >>= 1) s += __shfl_xor(s, off);
  float is = 1.0f / s;
  if (*flag) {
    float2 o; o.x = e0 * is; o.y = e1 * is;
    ((float2*)out)[(size_t)row * 64 + lane] = o;
  } else {
    ((u32*)out)[(size_t)row * 64 + lane] = f2bf_rne(e0 * is) | (f2bf_rne(e1 * is) << 16);
  }
}

// ---------------- launch ----------------

extern "C" void kernel_launch(void* const* d_in, const int* in_sizes, int n_in,
                              void* d_out, int out_size, void* d_ws, size_t ws_size,
                              hipStream_t stream) {
  const void* feats = d_in[0];
  const void* W = d_in[1];
  const void* bias = d_in[2];
  const void* wve = d_in[3];
  const void* wev = d_in[4];
  const int* pv = (const int*)d_in[5];
  const int* pe = (const int*)d_in[6];

  char* p = (char*)d_ws;
  auto alloc = [&](size_t b) { char* r = p; p += (b + 255) & ~(size_t)255; return r; };
  int* flag = (int*)alloc(4);
  // big region: binned scratch (2 x 25.2MB, used only during CSR build)
  // aliases xb (51.2MB) + yb (12.8MB), first written by the GEMM afterwards.
  char* big = alloc(64000000);
  u16* xb = (u16*)big;                          // bf16 [N][128]
  u16* yb = (u16*)(big + 51200000);             // bf16 [E][128]
  int2* binned0 = (int2*)big;                   // NB*CAP edge-dir records
  int2* binned1 = binned0 + (size_t)NB * CAP;   // NB*CAP vertex-dir records
  u16* wtg = (u16*)alloc(HG_D * HG_F * 2);      // canonical W^T bf16
  int* rpe = (int*)alloc((HG_E + 1) * 4);
  int* rpv = (int*)alloc((HG_N + 1) * 4);
  int2* ente = (int2*)alloc((size_t)HG_NNZ * 8);
  int2* entv = (int2*)alloc((size_t)HG_NNZ * 8);
  int* gcur = (int*)alloc(2 * NB * 4);
  // total ~97 MB

  detect_dtype<<<1, 256, 0, stream>>>((const u16*)feats, flag);

  // CSR build: bin -> per-bucket scatter (both directions merged per launch)
  hipMemsetAsync(gcur, 0, 2 * NB * 4, stream);
  int nb1 = (HG_NNZ + CHUNK - 1) / CHUNK;
  bin_pass1<<<2 * nb1, 256, 0, stream>>>(pv, pe, wve, wev, flag, binned0, binned1, gcur, nb1);
  csr_pass2<<<2 * NB, 256, 0, stream>>>(binned0, binned1, gcur, rpe, rpv, ente, entv);

  // x = feats @ W + b
  transpose_w_kernel<<<128, 256, 0, stream>>>(W, wtg, flag);
  gemm_kernel<false><<<1024, 256, 0, stream>>>(feats, wtg, bias, flag, xb);
  gemm_kernel<true><<<1024, 256, 0, stream>>>(feats, wtg, bias, flag, xb);

  // two hops of weighted-mean aggregation (last hop fused with softmax)
  pull_kernel<<<HG_E / 4, 256, 0, stream>>>(rpe, ente, (const u32*)xb, (u32*)yb, HG_E);
  pull_kernel<<<HG_N / 4, 256, 0, stream>>>(rpv, entv, (const u32*)yb, (u32*)xb, HG_N);
  pull_kernel<<<HG_E / 4, 256, 0, stream>>>(rpe, ente, (const u32*)xb, (u32*)yb, HG_E);
  pull_softmax_kernel<<<HG_N / 4, 256, 0, stream>>>(rpv, entv, (const u32*)yb, d_out, flag, HG_N);
}

// Round 4
// 791.116 us; speedup vs baseline: 1.3737x; 1.0704x over previous
//
#include <hip/hip_runtime.h>
#include <hip/hip_bf16.h>

typedef unsigned short u16;
typedef unsigned int u32;
typedef unsigned char u8;
typedef __attribute__((ext_vector_type(4))) float f32x4;
typedef __attribute__((ext_vector_type(8))) short s16x8;

#define HG_N   200000
#define HG_E   50000
#define HG_NNZ 2000000
#define HG_F   256
#define HG_D   128

// ---- binned CSR build geometry ----
#define NB     256
#define CHUNK  4096           // pairs per pass1 block (32KB LDS stage -> 3 blocks/CU)
#define CAP    12288
#define NSTRIP (HG_N / 16)    // 12500 GEMM row-strips

__device__ __forceinline__ u32 f2bf_rne(float x) {
  u32 u = __float_as_uint(x);
  return (u + 0x7fffu + ((u >> 16) & 1u)) >> 16;
}
__device__ __forceinline__ float bf2f(u32 bits) { return __uint_as_float(bits << 16); }
__device__ __forceinline__ float bf_lo(u32 u) { return __uint_as_float(u << 16); }
__device__ __forceinline__ float bf_hi(u32 u) { return __uint_as_float(u & 0xffff0000u); }

// ---------------- dtype detection ----------------
__global__ void detect_dtype(const u16* __restrict__ f, int* __restrict__ flag) {
  __shared__ int acc[4];
  int t = threadIdx.x;
  int bad = 0;
  for (int i = t; i < 2048; i += 256) {
    u32 u = f[2 * i];
    int e = (u >> 7) & 0xff;
    if (e < 0x70 || e > 0x88) bad++;
  }
#pragma unroll
  for (int off = 32; off; off >>= 1) bad += __shfl_down(bad, off);
  if ((t & 63) == 0) acc[t >> 6] = bad;
  __syncthreads();
  if (t == 0) flag[0] = (acc[0] + acc[1] + acc[2] + acc[3] > 200) ? 1 : 0;
}

// ---------------- CSR build: bucket-binned two-pass scatter ----------------

__global__ __launch_bounds__(256) void bin_pass1(
    const int* __restrict__ pv, const int* __restrict__ pe,
    const void* __restrict__ wve, const void* __restrict__ wev,
    const int* __restrict__ flag,
    int2* __restrict__ binned0, int2* __restrict__ binned1,
    int* __restrict__ gcur, int nb1) {
  __shared__ int cnt[NB], lbase[NB], run[NB], gbase[NB], sc[NB];
  __shared__ int2 stage[CHUNK];     // 32 KB, records sorted by bucket
  __shared__ u8 sb[CHUNK];          // bucket id per staged record
  int t = threadIdx.x;
  int dir = blockIdx.x >= nb1;
  int cb = dir ? blockIdx.x - nb1 : blockIdx.x;
  int base = cb * CHUNK;
  int n = HG_NNZ - base; if (n > CHUNK) n = CHUNK;
  int shift = dir ? 10 : 8;
  int mask = (1 << shift) - 1;
  const int* key = dir ? pv : pe;   // segment id (destination)
  const int* col = dir ? pe : pv;   // gather column
  const float* wf = (const float*)(dir ? wev : wve);
  const u16* wh = (const u16*)(dir ? wev : wve);
  int2* binned = dir ? binned1 : binned0;
  int* gc = gcur + (dir ? NB : 0);
  int fp32 = *flag;

  cnt[t] = 0;
  __syncthreads();

  // sweep 1: LDS histogram of buckets
#pragma unroll 4
  for (int k = 0; k < CHUNK / 256; ++k) {
    int p = base + k * 256 + t;
    if (p < HG_NNZ) atomicAdd(&cnt[key[p] >> shift], 1);
  }
  __syncthreads();

  // exclusive block scan of cnt -> lbase
  sc[t] = cnt[t];
  __syncthreads();
  for (int off = 1; off < NB; off <<= 1) {
    int x = (t >= off) ? sc[t - off] : 0;
    __syncthreads();
    sc[t] += x;
    __syncthreads();
  }
  lbase[t] = sc[t] - cnt[t];
  run[t] = lbase[t];
  gbase[t] = atomicAdd(&gc[t], cnt[t]);  // reserve run range per bucket
  __syncthreads();

  // sweep 2: rank + stage records into LDS (bucket-sorted)
#pragma unroll 4
  for (int k = 0; k < CHUNK / 256; ++k) {
    int p = base + k * 256 + t;
    if (p < HG_NNZ) {
      int kk = key[p];
      int b = kk >> shift;
      int local = kk & mask;
      float w = fp32 ? wf[p] : bf2f(wh[p]);
      int s = atomicAdd(&run[b], 1);
      int2 r; r.x = col[p] | (local << 18); r.y = __float_as_int(w);
      stage[s] = r;
      sb[s] = (u8)b;
    }
  }
  __syncthreads();

  // coalesced write-out of bucket-sorted runs
  for (int i = t; i < n; i += 256) {
    int bb = sb[i];
    int d = gbase[bb] + (i - lbase[bb]);
    if (d < CAP) binned[(size_t)bb * CAP + d] = stage[i];
  }
}

// Pass 2 (both directions, 512 blocks): one block per bucket.
__global__ __launch_bounds__(256) void csr_pass2(
    const int2* __restrict__ binned0, const int2* __restrict__ binned1,
    const int* __restrict__ gcur,
    int* __restrict__ rpe, int* __restrict__ rpv,
    int2* __restrict__ ente, int2* __restrict__ entv) {
  __shared__ int cc[NB], sc[NB];
  __shared__ int lcnt[1024], lrp[1024];
  int t = threadIdx.x;
  int dir = blockIdx.x >> 8;
  int b = blockIdx.x & 255;
  int shift = dir ? 10 : 8;
  int span = 1 << shift;
  int K = dir ? HG_N : HG_E;
  const int2* binned = dir ? binned1 : binned0;
  const int* gc = gcur + (dir ? NB : 0);
  int* rp = dir ? rpv : rpe;
  int2* ent = dir ? entv : ente;

  // scan bucket totals to get this bucket's global CSR base
  cc[t] = gc[t];
  __syncthreads();
  sc[t] = cc[t];
  __syncthreads();
  for (int off = 1; off < NB; off <<= 1) {
    int x = (t >= off) ? sc[t - off] : 0;
    __syncthreads();
    sc[t] += x;
    __syncthreads();
  }
  int gb = sc[b] - cc[b];
  int total = cc[b]; if (total > CAP) total = CAP;

  for (int j = t; j < 1024; j += 256) lcnt[j] = 0;
  __syncthreads();

  int kb = b << shift;
  int span_act = K - kb; if (span_act > span) span_act = span;
  const int2* rec = binned + (size_t)b * CAP;

  // local histogram over this bucket's segments
#pragma unroll 4
  for (int i = t; i < total; i += 256) atomicAdd(&lcnt[rec[i].x >> 18], 1);
  __syncthreads();

  // exclusive scan of lcnt[0..1024) -> lrp
  int vals[4], s0 = 0;
#pragma unroll
  for (int j = 0; j < 4; ++j) { vals[j] = lcnt[t * 4 + j]; s0 += vals[j]; }
  sc[t] = s0;
  __syncthreads();
  for (int off = 1; off < NB; off <<= 1) {
    int x = (t >= off) ? sc[t - off] : 0;
    __syncthreads();
    sc[t] += x;
    __syncthreads();
  }
  int running = sc[t] - s0;
#pragma unroll
  for (int j = 0; j < 4; ++j) { lrp[t * 4 + j] = running; running += vals[j]; }
  __syncthreads();

  // emit row pointers (boundary rows written consistently by both neighbors)
  for (int j = t; j <= span_act; j += 256)
    rp[kb + j] = gb + ((j < 1024) ? lrp[j] : total);
  __syncthreads();

  // scatter into this bucket's CSR slice
#pragma unroll 4
  for (int i = t; i < total; i += 256) {
    int2 r = rec[i];
    int local = r.x >> 18;
    int slot = gb + atomicAdd(&lrp[local], 1);
    int2 o; o.x = r.x & 0x3FFFF; o.y = r.y;
    ent[slot] = o;
  }
}

// ---------------- GEMM: x = feats @ W + b (bf16 MFMA, bf16 out) ----------------

__global__ void transpose_w_kernel(const void* __restrict__ W, u16* __restrict__ WT,
                                   const int* __restrict__ flag) {
  int idx = blockIdx.x * 256 + threadIdx.x;  // 256*128 = 32768 elems
  u16 v = (*flag) ? (u16)f2bf_rne(((const float*)W)[idx]) : ((const u16*)W)[idx];
  WT[(idx & 127) * 256 + (idx >> 7)] = v;
}

// 256-thread blocks, no occupancy bound (r2's (512,4) clamped VGPR to 64 ->
// scratch spills). Ping-pong prefetch: all 8 of the next strip's 16B A-loads
// issue before this strip's 64 MFMAs, so loads stay in flight across
// compute+store and only iteration 0's latency is exposed.
template <bool FP32>
__global__ __launch_bounds__(256) void gemm_kernel(
    const void* __restrict__ A,    // feats [N][256] (bf16 or fp32 per flag)
    const u16* __restrict__ WT,    // bf16 [128][256] (W transposed, canonical)
    const void* __restrict__ bias, // [128]
    const int* __restrict__ flag,
    u16* __restrict__ xb) {        // bf16 [N][128]
  if ((*flag != 0) != FP32) return;
  __shared__ u16 wt[32768];
  {
    const uint4* src = (const uint4*)WT;  // 4096 granules, 32 per row
    uint4* d = (uint4*)wt;
    for (int i = threadIdx.x; i < 4096; i += 256) {
      int r = i >> 5, g = i & 31;
      d[(r << 5) | (g ^ (r & 31))] = src[i];
    }
  }
  __syncthreads();
  int lane = threadIdx.x & 63;
  int q = lane >> 4, m = lane & 15;
  int wave0 = blockIdx.x * 4 + (threadIdx.x >> 6);
  int nwaves = gridDim.x * 4;
  const s16x8* wlds = (const s16x8*)wt;

  float bv[8];
#pragma unroll
  for (int n = 0; n < 8; ++n)
    bv[n] = FP32 ? ((const float*)bias)[n * 16 + m] : bf2f(((const u16*)bias)[n * 16 + m]);

  auto aload = [&](int s, int k0) -> s16x8 {
    if (FP32) {
      const float* ar = (const float*)A + (size_t)(s * 16 + m) * 256 + q * 8 + k0 * 32;
      float4 p0 = *(const float4*)ar;
      float4 p1 = *(const float4*)(ar + 4);
      s16x8 r;
      r[0] = (short)f2bf_rne(p0.x); r[1] = (short)f2bf_rne(p0.y);
      r[2] = (short)f2bf_rne(p0.z); r[3] = (short)f2bf_rne(p0.w);
      r[4] = (short)f2bf_rne(p1.x); r[5] = (short)f2bf_rne(p1.y);
      r[6] = (short)f2bf_rne(p1.z); r[7] = (short)f2bf_rne(p1.w);
      return r;
    } else {
      return *(const s16x8*)((const u16*)A + (size_t)(s * 16 + m) * 256 + q * 8 + k0 * 32);
    }
  };

  int strip = wave0;
  if (strip >= NSTRIP) return;
  s16x8 a[8], an[8];
#pragma unroll
  for (int k0 = 0; k0 < 8; ++k0) a[k0] = aload(strip, k0);

  for (; strip < NSTRIP; strip += nwaves) {
    int snext = strip + nwaves;
    int sp = (snext < NSTRIP) ? snext : strip;  // tail: harmless re-read
#pragma unroll
    for (int k0 = 0; k0 < 8; ++k0) an[k0] = aload(sp, k0);

    f32x4 acc[8];
#pragma unroll
    for (int n = 0; n < 8; ++n) acc[n] = (f32x4){0.f, 0.f, 0.f, 0.f};
#pragma unroll
    for (int k0 = 0; k0 < 8; ++k0) {
      int g = (k0 << 2) | q;
#pragma unroll
      for (int n = 0; n < 8; ++n) {
        int rr = n * 16 + m;  // B col index; WT row
        s16x8 b = wlds[(rr << 5) | (g ^ (rr & 31))];
        acc[n] = __builtin_amdgcn_mfma_f32_16x16x32_bf16(a[k0], b, acc[n], 0, 0, 0);
      }
    }
#pragma unroll
    for (int n = 0; n < 8; ++n) {
#pragma unroll
      for (int r = 0; r < 4; ++r) {
        // C/D layout: col = lane&15, row = (lane>>4)*4 + r  [m89/m91 verified]
        xb[(size_t)(strip * 16 + q * 4 + r) * 128 + n * 16 + m] = (u16)f2bf_rne(acc[n][r] + bv[n]);
      }
    }
#pragma unroll
    for (int k0 = 0; k0 < 8; ++k0) a[k0] = an[k0];
  }
}

// ---------------- Pull aggregation: quad-entry wide gathers ----------------
// One wave per destination row. 16 lanes x dwordx4 (16B) cover a 256B source
// row, so a 64-lane wave gathers FOUR entries per VMEM instruction (the old
// form was 64 lanes x dword = one entry per instruction -> 4x the instruction
// count, issue/latency bound on the L2/L3 gather path). Two quads (8 entries,
// 2KB) are kept in flight per iteration. Lane sub=lane&15 accumulates
// channels 8*sub..8*sub+7 in fp32; a shfl_xor(16,32) butterfly folds the 4
// entry-groups; group 0 writes the 256B row as one uint4 per lane.

__device__ __forceinline__ void pull_row_accum(
    const int2* __restrict__ ent, const u32* __restrict__ src,
    int beg, int end, int grp, int sub, float* acc, float& den) {
  for (int j = beg; j < end; j += 8) {
    int j0 = j + grp, j1 = j + 4 + grp;
    int2 e0 = ent[(j0 < end) ? j0 : (end - 1)];
    int2 e1 = ent[(j1 < end) ? j1 : (end - 1)];
    float w0 = (j0 < end) ? __int_as_float(e0.y) : 0.f;
    float w1 = (j1 < end) ? __int_as_float(e1.y) : 0.f;
    uint4 ua = *(const uint4*)(src + (size_t)e0.x * 64 + (sub << 2));
    uint4 ub = *(const uint4*)(src + (size_t)e1.x * 64 + (sub << 2));
    den += w0 + w1;
    acc[0] = fmaf(w0, bf_lo(ua.x), acc[0]); acc[1] = fmaf(w0, bf_hi(ua.x), acc[1]);
    acc[2] = fmaf(w0, bf_lo(ua.y), acc[2]); acc[3] = fmaf(w0, bf_hi(ua.y), acc[3]);
    acc[4] = fmaf(w0, bf_lo(ua.z), acc[4]); acc[5] = fmaf(w0, bf_hi(ua.z), acc[5]);
    acc[6] = fmaf(w0, bf_lo(ua.w), acc[6]); acc[7] = fmaf(w0, bf_hi(ua.w), acc[7]);
    acc[0] = fmaf(w1, bf_lo(ub.x), acc[0]); acc[1] = fmaf(w1, bf_hi(ub.x), acc[1]);
    acc[2] = fmaf(w1, bf_lo(ub.y), acc[2]); acc[3] = fmaf(w1, bf_hi(ub.y), acc[3]);
    acc[4] = fmaf(w1, bf_lo(ub.z), acc[4]); acc[5] = fmaf(w1, bf_hi(ub.z), acc[5]);
    acc[6] = fmaf(w1, bf_lo(ub.w), acc[6]); acc[7] = fmaf(w1, bf_hi(ub.w), acc[7]);
  }
  // fold the 4 entry-groups (lanes with equal sub exchange)
#pragma unroll
  for (int c = 0; c < 8; ++c) {
    acc[c] += __shfl_xor(acc[c], 16);
    acc[c] += __shfl_xor(acc[c], 32);
  }
  den += __shfl_xor(den, 16);
  den += __shfl_xor(den, 32);
}

__global__ __launch_bounds__(256) void pull_kernel(
    const int* __restrict__ rp, const int2* __restrict__ ent,
    const u32* __restrict__ src, u32* __restrict__ dst, int nrows) {
  int row = blockIdx.x * 4 + (threadIdx.x >> 6);
  if (row >= nrows) return;
  int lane = threadIdx.x & 63;
  int grp = lane >> 4, sub = lane & 15;
  int beg = rp[row], end = rp[row + 1];
  float acc[8] = {0.f, 0.f, 0.f, 0.f, 0.f, 0.f, 0.f, 0.f};
  float den = 0.f;
  pull_row_accum(ent, src, beg, end, grp, sub, acc, den);
  if (grp == 0) {
    float inv = 1.0f / fmaxf(den, 1e-12f);
    uint4 o;
    o.x = f2bf_rne(acc[0] * inv) | (f2bf_rne(acc[1] * inv) << 16);
    o.y = f2bf_rne(acc[2] * inv) | (f2bf_rne(acc[3] * inv) << 16);
    o.z = f2bf_rne(acc[4] * inv) | (f2bf_rne(acc[5] * inv) << 16);
    o.w = f2bf_rne(acc[6] * inv) | (f2bf_rne(acc[7] * inv) << 16);
    *(uint4*)(dst + (size_t)row * 64 + (sub << 2)) = o;
  }
}

// ---------------- Fused final pull + softmax ----------------
__global__ __launch_bounds__(256) void pull_softmax_kernel(
    const int* __restrict__ rp, const int2* __restrict__ ent,
    const u32* __restrict__ src, void* __restrict__ out,
    const int* __restrict__ flag, int nrows) {
  int row = blockIdx.x * 4 + (threadIdx.x >> 6);
  if (row >= nrows) return;
  int lane = threadIdx.x & 63;
  int grp = lane >> 4, sub = lane & 15;
  int beg = rp[row], end = rp[row + 1];
  float acc[8] = {0.f, 0.f, 0.f, 0.f, 0.f, 0.f, 0.f, 0.f};
  float den = 0.f;
  pull_row_accum(ent, src, beg, end, grp, sub, acc, den);
  // all lanes now hold the group-folded sums for their sub's 8 channels
  float inv = 1.0f / fmaxf(den, 1e-12f);
  float v[8];
#pragma unroll
  for (int c = 0; c < 8; ++c) v[c] = acc[c] * inv;
  float mx = v[0];
#pragma unroll
  for (int c = 1; c < 8; ++c) mx = fmaxf(mx, v[c]);
#pragma unroll
  for (int off = 1; off < 16; off <<= 1) mx = fmaxf(mx, __shfl_xor(mx, off));
  float e[8], s8 = 0.f;
#pragma unroll
  for (int c = 0; c < 8; ++c) { e[c] = __expf(v[c] - mx); s8 += e[c]; }
#pragma unroll
  for (int off = 1; off < 16; off <<= 1) s8 += __shfl_xor(s8, off);
  float is = 1.0f / s8;
  if (grp == 0) {
    if (*flag) {
      float4 oa, ob;
      oa.x = e[0] * is; oa.y = e[1] * is; oa.z = e[2] * is; oa.w = e[3] * is;
      ob.x = e[4] * is; ob.y = e[5] * is; ob.z = e[6] * is; ob.w = e[7] * is;
      ((float4*)out)[(size_t)row * 32 + sub * 2] = oa;
      ((float4*)out)[(size_t)row * 32 + sub * 2 + 1] = ob;
    } else {
      uint4 o;
      o.x = f2bf_rne(e[0] * is) | (f2bf_rne(e[1] * is) << 16);
      o.y = f2bf_rne(e[2] * is) | (f2bf_rne(e[3] * is) << 16);
      o.z = f2bf_rne(e[4] * is) | (f2bf_rne(e[5] * is) << 16);
      o.w = f2bf_rne(e[6] * is) | (f2bf_rne(e[7] * is) << 16);
      ((uint4*)out)[(size_t)row * 16 + sub] = o;
    }
  }
}

// ---------------- launch ----------------

extern "C" void kernel_launch(void* const* d_in, const int* in_sizes, int n_in,
                              void* d_out, int out_size, void* d_ws, size_t ws_size,
                              hipStream_t stream) {
  const void* feats = d_in[0];
  const void* W = d_in[1];
  const void* bias = d_in[2];
  const void* wve = d_in[3];
  const void* wev = d_in[4];
  const int* pv = (const int*)d_in[5];
  const int* pe = (const int*)d_in[6];

  char* p = (char*)d_ws;
  auto alloc = [&](size_t b) { char* r = p; p += (b + 255) & ~(size_t)255; return r; };
  int* flag = (int*)alloc(4);
  // big region: binned scratch (2 x 25.2MB, used only during CSR build)
  // aliases xb (51.2MB) + yb (12.8MB), first written by the GEMM afterwards.
  char* big = alloc(64000000);
  u16* xb = (u16*)big;                          // bf16 [N][128]
  u16* yb = (u16*)(big + 51200000);             // bf16 [E][128]
  int2* binned0 = (int2*)big;                   // NB*CAP edge-dir records
  int2* binned1 = binned0 + (size_t)NB * CAP;   // NB*CAP vertex-dir records
  u16* wtg = (u16*)alloc(HG_D * HG_F * 2);      // canonical W^T bf16
  int* rpe = (int*)alloc((HG_E + 1) * 4);
  int* rpv = (int*)alloc((HG_N + 1) * 4);
  int2* ente = (int2*)alloc((size_t)HG_NNZ * 8);
  int2* entv = (int2*)alloc((size_t)HG_NNZ * 8);
  int* gcur = (int*)alloc(2 * NB * 4);
  // total ~97 MB

  detect_dtype<<<1, 256, 0, stream>>>((const u16*)feats, flag);

  // CSR build: bin -> per-bucket scatter (both directions merged per launch)
  hipMemsetAsync(gcur, 0, 2 * NB * 4, stream);
  int nb1 = (HG_NNZ + CHUNK - 1) / CHUNK;
  bin_pass1<<<2 * nb1, 256, 0, stream>>>(pv, pe, wve, wev, flag, binned0, binned1, gcur, nb1);
  csr_pass2<<<2 * NB, 256, 0, stream>>>(binned0, binned1, gcur, rpe, rpv, ente, entv);

  // x = feats @ W + b
  transpose_w_kernel<<<128, 256, 0, stream>>>(W, wtg, flag);
  gemm_kernel<false><<<1024, 256, 0, stream>>>(feats, wtg, bias, flag, xb);
  gemm_kernel<true><<<1024, 256, 0, stream>>>(feats, wtg, bias, flag, xb);

  // two hops of weighted-mean aggregation (last hop fused with softmax)
  pull_kernel<<<HG_E / 4, 256, 0, stream>>>(rpe, ente, (const u32*)xb, (u32*)yb, HG_E);
  pull_kernel<<<HG_N / 4, 256, 0, stream>>>(rpv, entv, (const u32*)yb, (u32*)xb, HG_N);
  pull_kernel<<<HG_E / 4, 256, 0, stream>>>(rpe, ente, (const u32*)xb, (u32*)yb, HG_E);
  pull_softmax_kernel<<<HG_N / 4, 256, 0, stream>>>(rpv, entv, (const u32*)yb, d_out, flag, HG_N);
}